// Round 7
// baseline (197.843 us; speedup 1.0000x reference)
//
#include <hip/hip_runtime.h>
#include <stdint.h>

#define U 128
#define V 128
#define IN_STRIDE 512
#define OUT_STRIDE 512
#define W_STRIDE (8 * U * V) /* 131072 floats per expert */
#define NB 32768
#define NE 4

// Workspace layout (bytes)
#define WS_WSHUF 0           // 524288 ushorts (1 MB) shuffled bf16 weights
#define WS_CNT   1048576     // 4 uint per-expert cursors/counts (16 B)
#define WS_SORT  1048640     // 4 * 32768 ints (512 KB): region e at e*NB

typedef __bf16 bf16x8 __attribute__((ext_vector_type(8)));
typedef float f32x16 __attribute__((ext_vector_type(16)));
typedef unsigned int u32x4 __attribute__((ext_vector_type(4)));

static __device__ __forceinline__ unsigned short f2bf(float f) {
    unsigned int u = __builtin_bit_cast(unsigned int, f);
    u += 0x7FFFu + ((u >> 16) & 1u);   // round-to-nearest-even
    return (unsigned short)(u >> 16);
}

// ---------------------------------------------------------------------------
// prep (R8 layout): weights fp32 -> bf16 in 32x32x16 MFMA B-fragment layout.
//   shorts offset = (((e*8+s)*4+nt)*8+kt)*512 + lane*8 + j
//   element = W[e][s][k = kt*16+(lane>>5)*8+j][n = nt*32+(lane&31)], segs 4..7 x0.5
// ---------------------------------------------------------------------------
__global__ void prep_kernel(const float* __restrict__ w, unsigned short* __restrict__ wshuf,
                            unsigned int* __restrict__ cnt) {
    if (blockIdx.x == 0 && threadIdx.x < NE) cnt[threadIdx.x] = 0u;
    int t = blockIdx.x * 256 + threadIdx.x;   // 0..65535
    int lane = t & 63;
    int kt = (t >> 6) & 7;
    int nt = (t >> 9) & 3;
    int s  = (t >> 11) & 7;
    int e  = (t >> 14) & 3;
    int kbase = kt * 16 + ((lane >> 5) << 3);
    int n = nt * 32 + (lane & 31);
    const float* src = w + (size_t)e * W_STRIDE + (size_t)s * (U * V) + n;
    float sc = (s >= 4) ? 0.5f : 1.0f;
    __attribute__((aligned(16))) unsigned short o[8];
#pragma unroll
    for (int j = 0; j < 8; j++) o[j] = f2bf(src[(size_t)(kbase + j) * V] * sc);
    *(u32x4*)(wshuf + (size_t)t * 8) = *(const u32x4*)o;
}

// ---------------------------------------------------------------------------
// scatter: bucket rows by expert (order within expert irrelevant).
// ---------------------------------------------------------------------------
__global__ void scatter_kernel(const int* __restrict__ wid, unsigned int* __restrict__ cnt,
                               int* __restrict__ sorted) {
    __shared__ unsigned int lcnt[NE];
    __shared__ unsigned int lbase[NE];
    int t = threadIdx.x;
    if (t < NE) lcnt[t] = 0u;
    __syncthreads();
    int i = blockIdx.x * 256 + t;
    int e = wid[i];
    unsigned int lpos = atomicAdd(&lcnt[e], 1u);
    __syncthreads();
    if (t < NE) lbase[t] = atomicAdd(&cnt[t], lcnt[t]);
    __syncthreads();
    sorted[e * NB + (int)(lbase[e] + lpos)] = i;
}

// ---------------------------------------------------------------------------
// gemm R10: persistent 1-block/CU, 4-tile counted-vmcnt DMA pipeline (T3+T4).
// R8 (2-phase) = 38% HBM duty: read pipe idles during compute/store. R10:
// 256 blocks x 512 thr, block = 128 sorted rows = 4 tiles x 32 rows;
// LDS = double-buffered fp32 [2][32][512] (128 KB) so global_load_lds DMAs
// for tile T+1 are issued BEFORE computing tile T and stay in flight across
// the barrier (never drained mid-pipeline by construction of issue order):
//   per tile: [Bpre c0 (16 L2 loads, BEFORE DMAs so their consumption
//   doesn't drain DMAs)] [stores(T-1) (after Bpre so Bpre waits skip them)]
//   [DMA(T+1) x8] [compute c0 (Bpre) + c1 (inline B; its waits retire the
//   DMAs under compute)] [vmcnt(0) gate (free by then) + s_barrier].
// Stores of tile T issue after the next barrier -> overlap tile T+1 compute.
// Swizzle/layout/compute = R8 verbatim (verified): source-side XOR chunk
// swizzle, 32x32x16 MFMA, wave w = (kout=w>>1, nhalf=w&1).
// __launch_bounds__(512,2): VGPR<=256 (Bpre 64 + acc 32 + temps ~140).
// Fast single-expert path per tile; masked 4-expert path for <=3 boundary
// tiles (branch is block-uniform; barriers outside the branch).
// ---------------------------------------------------------------------------
__global__ __launch_bounds__(512, 2) void gemm_kernel(
        const float* __restrict__ x, const unsigned short* __restrict__ wshuf,
        const unsigned int* __restrict__ cnt, const int* __restrict__ sorted,
        float* __restrict__ out) {
    const int blk = blockIdx.x;
    __shared__ float ldsf[2][32][512];   // 128 KB double buffer
    __shared__ int rowid[128];

    const unsigned int p1 = cnt[0];
    const unsigned int p2 = p1 + cnt[1];
    const unsigned int p3 = p2 + cnt[2];

    const int t = threadIdx.x;
    const int w = t >> 6, lane = t & 63;
    const int l5 = lane >> 5, m0 = lane & 31;
    const int kout = w >> 1, nhalf = w & 1;
    const int rsw = m0 & 7;

    // ---- rowid for all 128 rows of this block ----
    if (t < 128) {
        unsigned int ls = (unsigned int)(blk * 128 + t);
        int e = (ls >= p1) + (ls >= p2) + (ls >= p3);
        unsigned int pe = (e == 0) ? 0u : (e == 1) ? p1 : (e == 2) ? p2 : p3;
        rowid[t] = sorted[e * NB + (int)(ls - pe)];
    }

    // ---- stage tile 0 (rid direct from sorted; no rowid dependence) ----
#pragma unroll
    for (int i = 0; i < 4; i++) {
        int r = 4 * w + i;
        unsigned int ls = (unsigned int)(blk * 128 + r);
        int e = (ls >= p1) + (ls >= p2) + (ls >= p3);
        unsigned int pe = (e == 0) ? 0u : (e == 1) ? p1 : (e == 2) ? p2 : p3;
        int rr = sorted[e * NB + (int)(ls - pe)];
        int rs = r & 7;
        const float* xb = x + (size_t)rr * IN_STRIDE + ((m0 ^ rs) << 2) + l5 * 128;
#pragma unroll
        for (int h = 0; h < 2; h++) {
            __builtin_amdgcn_global_load_lds(
                (const __attribute__((address_space(1))) unsigned int*)(xb + h * 256),
                (__attribute__((address_space(3))) unsigned int*)&ldsf[0][r][h * 256],
                16, 0, 0);
        }
    }

    // prologue gate: drain tile-0 DMAs + rowid ds_writes, then sync
    asm volatile("s_waitcnt vmcnt(0) lgkmcnt(0)" ::: "memory");
    __builtin_amdgcn_sched_barrier(0);
    __builtin_amdgcn_s_barrier();
    __builtin_amdgcn_sched_barrier(0);

    const int colb = kout * 128 + nhalf * 64 + m0;
    const int rh = l5 << 2;
    f32x16 acc0 = {}, acc1 = {};

    for (int T = 0; T < 4; T++) {
        const unsigned int rb = (unsigned int)(blk * 128 + T * 32);
        const int ehead = (rb >= p1) + (rb >= p2) + (rb >= p3);
        const unsigned int rte = rb + 31u;
        const int etail = (rte >= p1) + (rte >= p2) + (rte >= p3);
        const int fast = (ehead == etail);
        const int xb1 = (kout + 3) & 3;
        const float (*buf)[512] = ldsf[T & 1];

        if (fast) {
            // ---- Bpre c0: 16 L2 loads, issued BEFORE stores and DMAs ----
            const unsigned short* wb0 =
                wshuf + (size_t)(((ehead * 8 + kout) * 4 + nhalf * 2) * 8) * 512 + (size_t)lane * 8;
            u32x4 bp[16];
#pragma unroll
            for (int kt = 0; kt < 8; kt++) {
                bp[kt * 2]     = *(const u32x4*)(wb0 + (size_t)kt * 512);
                bp[kt * 2 + 1] = *(const u32x4*)(wb0 + (size_t)(8 + kt) * 512);
            }

            // ---- stores of tile T-1 (after Bpre: Bpre waits skip them) ----
            if (T > 0) {
#pragma unroll
                for (int q = 0; q < 4; q++)
#pragma unroll
                    for (int d = 0; d < 4; d++) {
                        int reg = q * 4 + d;
                        int rl = d + 8 * q + rh;
                        float* o = out + (size_t)rowid[(T - 1) * 32 + rl] * OUT_STRIDE + colb;
                        o[0]  = acc0[reg];
                        o[32] = acc1[reg];
                    }
                acc0 = (f32x16){};
                acc1 = (f32x16){};
            }

            // ---- DMA tile T+1 into other buffer ----
            if (T < 3) {
#pragma unroll
                for (int i = 0; i < 4; i++) {
                    int r = 4 * w + i;
                    int rr = rowid[(T + 1) * 32 + r];
                    int rs = r & 7;
                    const float* xb = x + (size_t)rr * IN_STRIDE + ((m0 ^ rs) << 2) + l5 * 128;
#pragma unroll
                    for (int h = 0; h < 2; h++) {
                        __builtin_amdgcn_global_load_lds(
                            (const __attribute__((address_space(1))) unsigned int*)(xb + h * 256),
                            (__attribute__((address_space(3))) unsigned int*)&ldsf[(T + 1) & 1][r][h * 256],
                            16, 0, 0);
                    }
                }
            }

            // ---- compute c0 (Bpre) ----
            {
                const float* ar = &buf[m0][kout * 128];
#pragma unroll
                for (int kt = 0; kt < 8; kt++) {
                    int gj0 = kt * 4 + l5 * 2;
                    float4 va = *(const float4*)(ar + ((gj0 ^ rsw) << 2));
                    float4 vb = *(const float4*)(ar + (((gj0 + 1) ^ rsw) << 2));
                    bf16x8 a;
                    a[0] = (__bf16)va.x; a[1] = (__bf16)va.y;
                    a[2] = (__bf16)va.z; a[3] = (__bf16)va.w;
                    a[4] = (__bf16)vb.x; a[5] = (__bf16)vb.y;
                    a[6] = (__bf16)vb.z; a[7] = (__bf16)vb.w;
                    bf16x8 b0 = __builtin_bit_cast(bf16x8, bp[kt * 2]);
                    bf16x8 b1 = __builtin_bit_cast(bf16x8, bp[kt * 2 + 1]);
                    acc0 = __builtin_amdgcn_mfma_f32_32x32x16_bf16(a, b0, acc0, 0, 0, 0);
                    acc1 = __builtin_amdgcn_mfma_f32_32x32x16_bf16(a, b1, acc1, 0, 0, 0);
                }
            }
            // ---- compute c1 (inline B; retires the DMAs under compute) ----
            {
                const unsigned short* wb1 =
                    wshuf + (size_t)(((ehead * 8 + xb1 + 4) * 4 + nhalf * 2) * 8) * 512 + (size_t)lane * 8;
                const float* ar = &buf[m0][xb1 * 128];
#pragma unroll
                for (int kt = 0; kt < 8; kt++) {
                    int gj0 = kt * 4 + l5 * 2;
                    float4 va = *(const float4*)(ar + ((gj0 ^ rsw) << 2));
                    float4 vb = *(const float4*)(ar + (((gj0 + 1) ^ rsw) << 2));
                    bf16x8 a;
                    a[0] = (__bf16)va.x; a[1] = (__bf16)va.y;
                    a[2] = (__bf16)va.z; a[3] = (__bf16)va.w;
                    a[4] = (__bf16)vb.x; a[5] = (__bf16)vb.y;
                    a[6] = (__bf16)vb.z; a[7] = (__bf16)vb.w;
                    bf16x8 b0 = __builtin_bit_cast(bf16x8, *(const u32x4*)(wb1 + (size_t)kt * 512));
                    bf16x8 b1 = __builtin_bit_cast(bf16x8, *(const u32x4*)(wb1 + (size_t)(8 + kt) * 512));
                    acc0 = __builtin_amdgcn_mfma_f32_32x32x16_bf16(a, b0, acc0, 0, 0, 0);
                    acc1 = __builtin_amdgcn_mfma_f32_32x32x16_bf16(a, b1, acc1, 0, 0, 0);
                }
            }
        } else {
            // ---- boundary tile: stores, DMA, masked 4-expert compute ----
            if (T > 0) {
#pragma unroll
                for (int q = 0; q < 4; q++)
#pragma unroll
                    for (int d = 0; d < 4; d++) {
                        int reg = q * 4 + d;
                        int rl = d + 8 * q + rh;
                        float* o = out + (size_t)rowid[(T - 1) * 32 + rl] * OUT_STRIDE + colb;
                        o[0]  = acc0[reg];
                        o[32] = acc1[reg];
                    }
                acc0 = (f32x16){};
                acc1 = (f32x16){};
            }
            if (T < 3) {
#pragma unroll
                for (int i = 0; i < 4; i++) {
                    int r = 4 * w + i;
                    int rr = rowid[(T + 1) * 32 + r];
                    int rs = r & 7;
                    const float* xb = x + (size_t)rr * IN_STRIDE + ((m0 ^ rs) << 2) + l5 * 128;
#pragma unroll
                    for (int h = 0; h < 2; h++) {
                        __builtin_amdgcn_global_load_lds(
                            (const __attribute__((address_space(1))) unsigned int*)(xb + h * 256),
                            (__attribute__((address_space(3))) unsigned int*)&ldsf[(T + 1) & 1][r][h * 256],
                            16, 0, 0);
                    }
                }
            }
            const unsigned int l0 = rb + (unsigned int)m0;
            const int e0 = (l0 >= p1) + (l0 >= p2) + (l0 >= p3);
            unsigned int msk[4];
#pragma unroll
            for (int e = 0; e < 4; e++) msk[e] = (e0 == e) ? 0xFFFFFFFFu : 0u;
            const int xbs[2] = {kout, xb1};
            const int sgs[2] = {kout, xb1 + 4};
#pragma unroll
            for (int c = 0; c < 2; c++) {
                const float* ar = &buf[m0][xbs[c] * 128];
#pragma unroll
                for (int kt = 0; kt < 8; kt++) {
                    int gj0 = kt * 4 + l5 * 2;
                    float4 va = *(const float4*)(ar + ((gj0 ^ rsw) << 2));
                    float4 vb = *(const float4*)(ar + (((gj0 + 1) ^ rsw) << 2));
                    __attribute__((aligned(16))) unsigned short au[8];
                    au[0] = f2bf(va.x); au[1] = f2bf(va.y);
                    au[2] = f2bf(va.z); au[3] = f2bf(va.w);
                    au[4] = f2bf(vb.x); au[5] = f2bf(vb.y);
                    au[6] = f2bf(vb.z); au[7] = f2bf(vb.w);
                    u32x4 araw = *(const u32x4*)au;
#pragma unroll
                    for (int e = 0; e < 4; e++) {
                        u32x4 mm = {msk[e], msk[e], msk[e], msk[e]};
                        bf16x8 am = __builtin_bit_cast(bf16x8, araw & mm);
                        const unsigned short* wbe =
                            wshuf + (size_t)(((e * 8 + sgs[c]) * 4 + nhalf * 2) * 8) * 512 + (size_t)lane * 8;
                        bf16x8 b0 = __builtin_bit_cast(bf16x8, *(const u32x4*)(wbe + (size_t)kt * 512));
                        bf16x8 b1 = __builtin_bit_cast(bf16x8, *(const u32x4*)(wbe + (size_t)(8 + kt) * 512));
                        acc0 = __builtin_amdgcn_mfma_f32_32x32x16_bf16(am, b0, acc0, 0, 0, 0);
                        acc1 = __builtin_amdgcn_mfma_f32_32x32x16_bf16(am, b1, acc1, 0, 0, 0);
                    }
                }
            }
        }

        // ---- inter-tile gate: DMAs already retired by c1's B waits ----
        if (T < 3) {
            asm volatile("s_waitcnt vmcnt(0)" ::: "memory");
            __builtin_amdgcn_sched_barrier(0);
            __builtin_amdgcn_s_barrier();
            __builtin_amdgcn_sched_barrier(0);
        }
    }

    // ---- final stores (tile 3) ----
#pragma unroll
    for (int q = 0; q < 4; q++)
#pragma unroll
        for (int d = 0; d < 4; d++) {
            int reg = q * 4 + d;
            int rl = d + 8 * q + rh;
            float* o = out + (size_t)rowid[3 * 32 + rl] * OUT_STRIDE + colb;
            o[0]  = acc0[reg];
            o[32] = acc1[reg];
        }
}

extern "C" void kernel_launch(void* const* d_in, const int* in_sizes, int n_in,
                              void* d_out, int out_size, void* d_ws, size_t ws_size,
                              hipStream_t stream) {
    const float* x = (const float*)d_in[0];
    const float* w = (const float*)d_in[1];
    const int* wid = (const int*)d_in[2];
    float* out = (float*)d_out;

    unsigned short* wshuf = (unsigned short*)((char*)d_ws + WS_WSHUF);
    unsigned int* cnt = (unsigned int*)((char*)d_ws + WS_CNT);
    int* sorted = (int*)((char*)d_ws + WS_SORT);

    prep_kernel<<<256, 256, 0, stream>>>(w, wshuf, cnt);
    scatter_kernel<<<128, 256, 0, stream>>>(wid, cnt, sorted);
    gemm_kernel<<<256, 512, 0, stream>>>(x, wshuf, cnt, sorted, out);
}

// Round 8
// 143.345 us; speedup vs baseline: 1.3802x; 1.3802x over previous
//
#include <hip/hip_runtime.h>
#include <stdint.h>

#define U 128
#define V 128
#define IN_STRIDE 512
#define OUT_STRIDE 512
#define W_STRIDE (8 * U * V) /* 131072 floats per expert */
#define NB 32768
#define NE 4

// Workspace layout (bytes)
#define WS_WSHUF 0           // 524288 ushorts (1 MB) shuffled bf16 weights
#define WS_CNT   1048576     // 4 uint per-expert cursors/counts (16 B)
#define WS_SORT  1048640     // 4 * 32768 ints (512 KB): region e at e*NB

typedef __bf16 bf16x8 __attribute__((ext_vector_type(8)));
typedef float f32x16 __attribute__((ext_vector_type(16)));
typedef unsigned int u32x4 __attribute__((ext_vector_type(4)));

static __device__ __forceinline__ unsigned short f2bf(float f) {
    unsigned int u = __builtin_bit_cast(unsigned int, f);
    u += 0x7FFFu + ((u >> 16) & 1u);   // round-to-nearest-even
    return (unsigned short)(u >> 16);
}

// ---------------------------------------------------------------------------
// prep (R8 layout, unchanged): weights fp32 -> bf16, 32x32x16 B-fragment order.
//   shorts offset = (((e*8+s)*4+nt)*8+kt)*512 + lane*8 + j
//   element = W[e][s][k = kt*16+(lane>>5)*8+j][n = nt*32+(lane&31)], segs 4..7 x0.5
// ---------------------------------------------------------------------------
__global__ void prep_kernel(const float* __restrict__ w, unsigned short* __restrict__ wshuf,
                            unsigned int* __restrict__ cnt) {
    if (blockIdx.x == 0 && threadIdx.x < NE) cnt[threadIdx.x] = 0u;
    int t = blockIdx.x * 256 + threadIdx.x;   // 0..65535
    int lane = t & 63;
    int kt = (t >> 6) & 7;
    int nt = (t >> 9) & 3;
    int s  = (t >> 11) & 7;
    int e  = (t >> 14) & 3;
    int kbase = kt * 16 + ((lane >> 5) << 3);
    int n = nt * 32 + (lane & 31);
    const float* src = w + (size_t)e * W_STRIDE + (size_t)s * (U * V) + n;
    float sc = (s >= 4) ? 0.5f : 1.0f;
    __attribute__((aligned(16))) unsigned short o[8];
#pragma unroll
    for (int j = 0; j < 8; j++) o[j] = f2bf(src[(size_t)(kbase + j) * V] * sc);
    *(u32x4*)(wshuf + (size_t)t * 8) = *(const u32x4*)o;
}

// ---------------------------------------------------------------------------
// scatter: bucket rows by expert (order within expert irrelevant).
// ---------------------------------------------------------------------------
__global__ void scatter_kernel(const int* __restrict__ wid, unsigned int* __restrict__ cnt,
                               int* __restrict__ sorted) {
    __shared__ unsigned int lcnt[NE];
    __shared__ unsigned int lbase[NE];
    int t = threadIdx.x;
    if (t < NE) lcnt[t] = 0u;
    __syncthreads();
    int i = blockIdx.x * 256 + t;
    int e = wid[i];
    unsigned int lpos = atomicAdd(&lcnt[e], 1u);
    __syncthreads();
    if (t < NE) lbase[t] = atomicAdd(&cnt[t], lcnt[t]);
    __syncthreads();
    sorted[e * NB + (int)(lbase[e] + lpos)] = i;
}

// ---------------------------------------------------------------------------
// gemm R11: break the 2-block convoy with many small phase-staggered blocks.
// Evidence: R8 (2-phase, 2 big blocks/CU) = 44us at 40% HBM duty, occupancy
// 26% (waves parked at the one barrier in phase); R7/R9/R10 pipelining all
// regressed. R11 keeps R8's exact 2-phase skeleton but: block = 4 waves =
// ONE kout (32 sorted rows x 128 out cols), staging only the 2 x-blocks this
// kout consumes -> LDS [2][32][128] fp32 = 32 KB. 4096 blocks (rg=bid>>2,
// kout=bid&3), __launch_bounds__(256,4) -> 4 blocks/CU co-resident (132 KB
// LDS, VGPR<=128), 16 waves/CU, 16 generations: 4 independently-phased
// stage->drain->compute cycles per CU hide each other's HBM latency.
// ALL 16 B-fragments preloaded to VGPR before the barrier (R8 was VGPR-capped
// at 60 and could only hold 8): compute phase has ZERO global loads.
// DMA: per instr lanes 0-31 -> row r, lanes 32-63 -> row r+1 (dest linear,
// 512B apart in [2][32][128]); source-side XOR chunk swizzle (rule #21):
// LDS chunk q of row r holds global chunk q^(r&7); fragment read XORs back.
// x is read by 2 blocks (c0 of kout, c1 of (kout+1)&3) -> 2nd read L3-hits
// (x=64MB < 256MB L3). Stores: 128B segments, same as R8 (WRITE was exactly
// 64MB there). Fast single-expert path; masked 4-expert path for <=3
// boundary row-groups (block-uniform branch).
// ---------------------------------------------------------------------------
__global__ __launch_bounds__(256, 4) void gemm_kernel(
        const float* __restrict__ x, const unsigned short* __restrict__ wshuf,
        const unsigned int* __restrict__ cnt, const int* __restrict__ sorted,
        float* __restrict__ out) {
    const int bid = blockIdx.x;
    const int rg = bid >> 2;          // row-group 0..1023
    const int kout = bid & 3;         // output col block
    const int rowbase = rg * 32;
    __shared__ float ldsf[2][32][128];   // 32 KB: [c][row][col]
    __shared__ int rowid[32];

    const unsigned int p1 = cnt[0];
    const unsigned int p2 = p1 + cnt[1];
    const unsigned int p3 = p2 + cnt[2];

    const int t = threadIdx.x;
    const int w = t >> 6, lane = t & 63;
    const int l5 = lane >> 5, m0 = lane & 31;
    const int rsw = m0 & 7;

    const int xb1 = (kout + 3) & 3;
    const int xbs[2] = {kout, xb1};
    const int sgs[2] = {kout, xb1 + 4};

    // ---- rowid for the 32 rows ----
    if (t < 32) {
        unsigned int ls = (unsigned int)(rowbase + t);
        int e = (ls >= p1) + (ls >= p2) + (ls >= p3);
        unsigned int pe = (e == 0) ? 0u : (e == 1) ? p1 : (e == 2) ? p2 : p3;
        rowid[t] = sorted[e * NB + (int)(ls - pe)];
    }

    // ---- stage: wave w stages row-pairs {w*4+i : i<4}, both x-blocks ----
    // per instr: lanes 0-31 -> row r0 (chunk swz r0&7), lanes 32-63 -> r0+1
#pragma unroll
    for (int i = 0; i < 4; i++) {
        int r0 = (w * 4 + i) * 2;
        int rl_ = r0 + l5;                 // this lane's row
        unsigned int ls = (unsigned int)(rowbase + rl_);
        int e = (ls >= p1) + (ls >= p2) + (ls >= p3);
        unsigned int pe = (e == 0) ? 0u : (e == 1) ? p1 : (e == 2) ? p2 : p3;
        int rr = sorted[e * NB + (int)(ls - pe)];
        int rs = rl_ & 7;
        const float* xr = x + (size_t)rr * IN_STRIDE + ((m0 ^ rs) << 2);
#pragma unroll
        for (int c = 0; c < 2; c++) {
            __builtin_amdgcn_global_load_lds(
                (const __attribute__((address_space(1))) unsigned int*)(xr + xbs[c] * 128),
                (__attribute__((address_space(3))) unsigned int*)&ldsf[c][r0][0],
                16, 0, 0);
        }
    }

    // expert span / per-lane expert
    const unsigned int lh = (unsigned int)rowbase, lt = (unsigned int)(rowbase + 31);
    const int ehead = (lh >= p1) + (lh >= p2) + (lh >= p3);
    const int etail = (lt >= p1) + (lt >= p2) + (lt >= p3);
    const unsigned int l0 = (unsigned int)(rowbase + m0);
    const int e0 = (l0 >= p1) + (l0 >= p2) + (l0 >= p3);

    f32x16 acc = {};   // D cols kout*128 + w*32 + (lane&31)

    if (ehead == etail) {
        // ---- fast path: preload ALL 16 B-frags (nt = w) before barrier ----
        u32x4 bp[16];
#pragma unroll
        for (int c = 0; c < 2; c++) {
            const unsigned short* wb =
                wshuf + ((size_t)((ehead * 8 + sgs[c]) * 4 + w) * 8) * 512 + (size_t)lane * 8;
#pragma unroll
            for (int kt = 0; kt < 8; kt++)
                bp[c * 8 + kt] = *(const u32x4*)(wb + (size_t)kt * 512);
        }

        __syncthreads();   // drains x-DMAs + B-preloads + rowid writes

        // ---- compute: 16 MFMAs, zero global loads ----
#pragma unroll
        for (int c = 0; c < 2; c++) {
            const float* ar = &ldsf[c][m0][0];
#pragma unroll
            for (int kt = 0; kt < 8; kt++) {
                int gj0 = kt * 4 + l5 * 2;
                float4 va = *(const float4*)(ar + ((gj0 ^ rsw) << 2));
                float4 vb = *(const float4*)(ar + (((gj0 + 1) ^ rsw) << 2));
                bf16x8 a;
                a[0] = (__bf16)va.x; a[1] = (__bf16)va.y;
                a[2] = (__bf16)va.z; a[3] = (__bf16)va.w;
                a[4] = (__bf16)vb.x; a[5] = (__bf16)vb.y;
                a[6] = (__bf16)vb.z; a[7] = (__bf16)vb.w;
                bf16x8 b = __builtin_bit_cast(bf16x8, bp[c * 8 + kt]);
                acc = __builtin_amdgcn_mfma_f32_32x32x16_bf16(a, b, acc, 0, 0, 0);
            }
        }
    } else {
        // ---- boundary row-group (<=3 of 1024, x4 kouts): masked path ----
        unsigned int msk[4];
#pragma unroll
        for (int e = 0; e < 4; e++) msk[e] = (e0 == e) ? 0xFFFFFFFFu : 0u;
        __syncthreads();
#pragma unroll
        for (int c = 0; c < 2; c++) {
            const float* ar = &ldsf[c][m0][0];
#pragma unroll
            for (int kt = 0; kt < 8; kt++) {
                int gj0 = kt * 4 + l5 * 2;
                float4 va = *(const float4*)(ar + ((gj0 ^ rsw) << 2));
                float4 vb = *(const float4*)(ar + (((gj0 + 1) ^ rsw) << 2));
                __attribute__((aligned(16))) unsigned short au[8];
                au[0] = f2bf(va.x); au[1] = f2bf(va.y);
                au[2] = f2bf(va.z); au[3] = f2bf(va.w);
                au[4] = f2bf(vb.x); au[5] = f2bf(vb.y);
                au[6] = f2bf(vb.z); au[7] = f2bf(vb.w);
                u32x4 araw = *(const u32x4*)au;
#pragma unroll
                for (int e = 0; e < 4; e++) {
                    u32x4 mm = {msk[e], msk[e], msk[e], msk[e]};
                    bf16x8 am = __builtin_bit_cast(bf16x8, araw & mm);
                    const unsigned short* wbe =
                        wshuf + ((size_t)((e * 8 + sgs[c]) * 4 + w) * 8) * 512 + (size_t)lane * 8;
                    bf16x8 b = __builtin_bit_cast(bf16x8, *(const u32x4*)(wbe + (size_t)kt * 512));
                    acc = __builtin_amdgcn_mfma_f32_32x32x16_bf16(am, b, acc, 0, 0, 0);
                }
            }
        }
    }

    // ---- epilogue: C/D layout col=lane&31, row=(reg&3)+8*(reg>>2)+4*(lane>>5)
    // per store instr: 2 x 128B contiguous segments (rows via rowid).
    const int colb = kout * 128 + w * 32 + m0;
    const int rh = l5 << 2;
#pragma unroll
    for (int q = 0; q < 4; q++) {
#pragma unroll
        for (int d = 0; d < 4; d++) {
            int reg = q * 4 + d;
            int rl = d + 8 * q + rh;
            out[(size_t)rowid[rl] * OUT_STRIDE + colb] = acc[reg];
        }
    }
}

extern "C" void kernel_launch(void* const* d_in, const int* in_sizes, int n_in,
                              void* d_out, int out_size, void* d_ws, size_t ws_size,
                              hipStream_t stream) {
    const float* x = (const float*)d_in[0];
    const float* w = (const float*)d_in[1];
    const int* wid = (const int*)d_in[2];
    float* out = (float*)d_out;

    unsigned short* wshuf = (unsigned short*)((char*)d_ws + WS_WSHUF);
    unsigned int* cnt = (unsigned int*)((char*)d_ws + WS_CNT);
    int* sorted = (int*)((char*)d_ws + WS_SORT);

    prep_kernel<<<256, 256, 0, stream>>>(w, wshuf, cnt);
    scatter_kernel<<<128, 256, 0, stream>>>(wid, cnt, sorted);
    gemm_kernel<<<4096, 256, 0, stream>>>(x, wshuf, cnt, sorted, out);
}